// Round 3
// baseline (492.661 us; speedup 1.0000x reference)
//
#include <hip/hip_runtime.h>
#include <math.h>

#define H_ 128
#define W_ 128
#define C_ 64
#define B_ 8
#define HW 16384          // H_*W_
#define NPIX (B_*HW)      // 131072

typedef __attribute__((ext_vector_type(8))) short short8;
typedef __attribute__((ext_vector_type(4))) float f32x4;

__device__ __forceinline__ float softplus_fast(float v) {
    // max(v,0) + log(1+exp(-|v|)), native v_exp_f32 / v_log_f32
    return fmaxf(v, 0.f) + __logf(1.f + __expf(-fabsf(v)));
}

__device__ __forceinline__ unsigned short f2bf(float f) {
    unsigned u = __builtin_bit_cast(unsigned, f);
    unsigned r = (u + 0x7fffu + ((u >> 16) & 1u)) >> 16;
    return (unsigned short)r;
}

// K0: transpose w2 [o][c][3][3] f32 -> bf16 MFMA A-fragments.
__global__ __launch_bounds__(256) void k0_wtr(const float* __restrict__ w2,
                                              unsigned short* __restrict__ wtr)
{
    int t = blockIdx.x * 256 + threadIdx.x;
    if (t >= 4 * 18 * 64) return;
    int lane = t & 63;
    int f    = (t >> 6) % 18;
    int wv   = t / (18 * 64);
    int koff = f >> 1, ch = f & 1;
    int o = wv * 16 + (lane & 15);
    int cb = ch * 32 + ((lane >> 4) << 3);
    uint4 pk;
    unsigned short* pv = (unsigned short*)&pk;
#pragma unroll
    for (int e = 0; e < 8; ++e)
        pv[e] = f2bf(w2[(size_t)o * 576 + (size_t)(cb + e) * 9 + koff]);
    *(uint4*)&wtr[(size_t)t * 8] = pk;
}

// K1: r = W_reduce @ x + b_reduce per pixel -> bf16 PIXEL-MAJOR [b][pix][c].
// Each thread owns one pixel, accumulates all 64 channels in regs, writes
// one contiguous 128B block.
__global__ __launch_bounds__(256) void k1_r(
    const float* __restrict__ x, const float* __restrict__ wr,
    const float* __restrict__ br, unsigned short* __restrict__ rb)
{
    __shared__ float wrs[C_ * C_];
    __shared__ float brs[C_];
    int tid = threadIdx.x;
    for (int i = tid; i < C_ * C_; i += 256) wrs[i] = wr[i];
    if (tid < C_) brs[tid] = br[tid];
    __syncthreads();

    int pid = blockIdx.x * 256 + tid;
    int b   = pid >> 14;
    int rem = pid & (HW - 1);
    const float* xp = x + (((size_t)b * C_) << 14) + rem;

    float xv[C_];
#pragma unroll
    for (int c = 0; c < C_; ++c) xv[c] = xp[(size_t)c << 14];

    unsigned pkk[C_ / 2];
#pragma unroll
    for (int o = 0; o < C_; ++o) {
        float acc = brs[o];
        const float4* wro = reinterpret_cast<const float4*>(&wrs[o * C_]);
#pragma unroll
        for (int c4 = 0; c4 < C_ / 4; ++c4) {
            float4 wv = wro[c4];
            acc += wv.x * xv[4*c4] + wv.y * xv[4*c4+1]
                 + wv.z * xv[4*c4+2] + wv.w * xv[4*c4+3];
        }
        unsigned short bv = f2bf(acc);
        if (o & 1) pkk[o >> 1] |= ((unsigned)bv << 16);
        else       pkk[o >> 1]  = bv;
    }
    uint4* rp = (uint4*)(rb + ((size_t)pid << 6));
#pragma unroll
    for (int jj = 0; jj < 8; ++jj) rp[jj] = ((uint4*)pkk)[jj];
}

// K1b: per-channel sum/sumsq over rb (bf16 pixel-major). Thread handles
// channel-octet j = tid&7 of pixels row + k*4096; register accumulators,
// shfl reduce across lanes sharing j, LDS stage, one global atomic set/block.
__global__ __launch_bounds__(256) void k1b_stats(
    const unsigned short* __restrict__ rb, float* __restrict__ stats)
{
    __shared__ float ls[128];
    int tid = threadIdx.x;
    if (tid < 128) ls[tid] = 0.f;
    __syncthreads();

    int j   = tid & 7;
    int row = (blockIdx.x << 5) + (tid >> 3);
    float s[8] = {0,0,0,0,0,0,0,0}, q[8] = {0,0,0,0,0,0,0,0};
    for (int p = row; p < NPIX; p += (gridDim.x << 5)) {
        uint4 v = *(const uint4*)(rb + ((size_t)p << 6) + (j << 3));
        const unsigned* u = (const unsigned*)&v;
#pragma unroll
        for (int e = 0; e < 4; ++e) {
            float lo = __builtin_bit_cast(float, u[e] << 16);
            float hi = __builtin_bit_cast(float, u[e] & 0xffff0000u);
            s[2*e]   += lo; q[2*e]   += lo * lo;
            s[2*e+1] += hi; q[2*e+1] += hi * hi;
        }
    }
#pragma unroll
    for (int e = 0; e < 8; ++e) {
#pragma unroll
        for (int m = 8; m <= 32; m <<= 1) {
            s[e] += __shfl_xor(s[e], m, 64);
            q[e] += __shfl_xor(q[e], m, 64);
        }
    }
    int lane = tid & 63;
    if (lane < 8) {
#pragma unroll
        for (int e = 0; e < 8; ++e) {
            atomicAdd(&ls[lane * 8 + e], s[e]);
            atomicAdd(&ls[64 + lane * 8 + e], q[e]);
        }
    }
    __syncthreads();
    if (tid < 128) atomicAdd(&stats[tid], ls[tid]);
}

// K3: BN-fold (inline), kern[9] from r; involution over 3x3 x-patches;
// fast softplus -> z bf16 pixel-major, one contiguous 128B write per thread.
__global__ __launch_bounds__(256) void k3_involution(
    const float* __restrict__ x, const unsigned short* __restrict__ rb,
    const float* __restrict__ stats, const float* __restrict__ gamma,
    const float* __restrict__ beta, const float* __restrict__ wspan,
    const float* __restrict__ bspan, unsigned short* __restrict__ zb)
{
    __shared__ float wst[C_ * 12];
    __shared__ float a_s[C_], c_s[C_];
    __shared__ float xt[8][18][19];
    int tid = threadIdx.x;
    for (int i = tid; i < 9 * C_; i += 256) {
        int k = i >> 6, o = i & 63;
        wst[o * 12 + k] = wspan[i];
    }
    if (tid < C_) {
        float inv_n = 1.f / (float)NPIX;
        float mu  = stats[tid] * inv_n;
        float var = stats[C_ + tid] * inv_n - mu * mu;
        float is  = rsqrtf(var + 1e-5f);
        float a   = gamma[tid] * is;
        a_s[tid] = a;
        c_s[tid] = beta[tid] - mu * a;
    }

    int blk = blockIdx.x;
    int b = blk >> 6;
    int t = blk & 63;
    int h0 = (t >> 3) << 4;
    int w0 = (t & 7) << 4;
    int ty = tid >> 4, tx = tid & 15;
    int h = h0 + ty, w = w0 + tx;
    int pix = (h << 7) + w;
    int pid = (b << 14) + pix;
    size_t base_b = ((size_t)b * C_) << 14;

    // load this pixel's 64 r values (bf16 packed)
    unsigned pkr[32];
    const uint4* rp = (const uint4*)(rb + ((size_t)pid << 6));
#pragma unroll
    for (int jj = 0; jj < 8; ++jj) ((uint4*)pkr)[jj] = rp[jj];

    __syncthreads();   // wst/a_s/c_s ready

    float kern[9];
#pragma unroll
    for (int k = 0; k < 9; ++k) kern[k] = bspan[k];
#pragma unroll
    for (int o = 0; o < C_; ++o) {
        unsigned pr = pkr[o >> 1];
        float rv = __builtin_bit_cast(float, (o & 1) ? (pr & 0xffff0000u) : (pr << 16));
        float rn = fmaxf(a_s[o] * rv + c_s[o], 0.f);
        const float* wo = &wst[o * 12];
#pragma unroll
        for (int k = 0; k < 9; ++k) kern[k] += wo[k] * rn;
    }

    unsigned zpk[32];
#pragma unroll
    for (int c0 = 0; c0 < C_; c0 += 8) {
        __syncthreads();
        for (int idx = tid; idx < 8 * 324; idx += 256) {
            int c  = idx / 324;
            int r2 = idx - c * 324;
            int ly = r2 / 18, lx = r2 - ly * 18;
            int gh = h0 + ly - 1, gw = w0 + lx - 1;
            float v = 0.f;
            if ((unsigned)gh < 128u && (unsigned)gw < 128u)
                v = x[base_b + ((size_t)(c0 + c) << 14) + (gh << 7) + gw];
            xt[c][ly][lx] = v;
        }
        __syncthreads();
#pragma unroll
        for (int c = 0; c < 8; ++c) {
            float acc = 0.f;
#pragma unroll
            for (int i = 0; i < 3; ++i)
#pragma unroll
                for (int j = 0; j < 3; ++j)
                    acc += kern[i * 3 + j] * xt[c][ty + i][tx + j];
            unsigned short bv = f2bf(softplus_fast(acc));
            int oc = c0 + c;
            if (oc & 1) zpk[oc >> 1] |= ((unsigned)bv << 16);
            else        zpk[oc >> 1]  = bv;
        }
    }
    uint4* zp = (uint4*)(zb + ((size_t)pid << 6));
#pragma unroll
    for (int jj = 0; jj < 8; ++jj) zp[jj] = ((uint4*)zpk)[jj];
}

// K4: dense 3x3 conv 64->64 via implicit-GEMM MFMA (bf16 in, f32 acc)
// + bias + softplus. 4 waves; wave w owns out-channels [16w,16w+16).
__global__ __launch_bounds__(256) void k4_mfma(
    const unsigned short* __restrict__ zb, const unsigned short* __restrict__ wtr,
    const float* __restrict__ b2, float* __restrict__ out)
{
    __shared__ unsigned short zt[324 * 64];   // 41,472 B, chunk-swizzled
    int tid = threadIdx.x;
    int blk = blockIdx.x;
    int b = blk >> 6;
    int t = blk & 63;
    int h0 = (t >> 3) << 4;
    int w0 = (t & 7) << 4;

    for (int idx = tid; idx < 324 * 8; idx += 256) {
        int p  = idx >> 3;
        int cg = idx & 7;
        int py = p / 18, px = p - py * 18;
        int gh = h0 + py - 1, gw = w0 + px - 1;
        uint4 v = make_uint4(0u, 0u, 0u, 0u);
        if ((unsigned)gh < 128u && (unsigned)gw < 128u)
            v = *(const uint4*)(zb + (((size_t)((b << 14) + (gh << 7) + gw)) << 6) + (cg << 3));
        *(uint4*)&zt[(p << 6) + ((cg ^ (p & 7)) << 3)] = v;
    }

    int wid  = tid >> 6, lane = tid & 63;
    int nl   = lane & 15;
    int kg   = lane >> 4;

    short8 wf[18];
    const short8* wp = (const short8*)wtr;
#pragma unroll
    for (int f = 0; f < 18; ++f)
        wf[f] = wp[(size_t)(wid * 18 + f) * 64 + lane];

    f32x4 acc[16];
#pragma unroll
    for (int nt = 0; nt < 16; ++nt) acc[nt] = (f32x4){0.f, 0.f, 0.f, 0.f};

    __syncthreads();

#pragma unroll
    for (int y = 0; y < 18; ++y) {
        short8 bf[6];
#pragma unroll
        for (int j = 0; j < 3; ++j)
#pragma unroll
            for (int ch = 0; ch < 2; ++ch) {
                int p  = y * 18 + j + nl;
                int cg = ch * 4 + kg;
                bf[j * 2 + ch] = *(const short8*)&zt[(p << 6) + ((cg ^ (p & 7)) << 3)];
            }
#pragma unroll
        for (int i = 0; i < 3; ++i) {
            int nt = y - i;
            if (nt >= 0 && nt < 16) {
#pragma unroll
                for (int j = 0; j < 3; ++j)
#pragma unroll
                    for (int ch = 0; ch < 2; ++ch)
                        acc[nt] = __builtin_amdgcn_mfma_f32_16x16x32_bf16(
                            wf[(i * 3 + j) * 2 + ch], bf[j * 2 + ch], acc[nt], 0, 0, 0);
            }
        }
    }

    float bias[4];
#pragma unroll
    for (int r = 0; r < 4; ++r) bias[r] = b2[(wid << 4) + (kg << 2) + r];

    size_t ob = ((size_t)b) << 20;
#pragma unroll
    for (int nt = 0; nt < 16; ++nt) {
        int h = h0 + nt;
#pragma unroll
        for (int r = 0; r < 4; ++r) {
            int o = (wid << 4) + (kg << 2) + r;
            float v = acc[nt][r] + bias[r];
            out[ob + ((size_t)o << 14) + (h << 7) + w0 + nl] = softplus_fast(v);
        }
    }
}

extern "C" void kernel_launch(void* const* d_in, const int* in_sizes, int n_in,
                              void* d_out, int out_size, void* d_ws, size_t ws_size,
                              hipStream_t stream)
{
    const float* x   = (const float*)d_in[0];
    const float* wr  = (const float*)d_in[1];
    const float* br  = (const float*)d_in[2];
    const float* gam = (const float*)d_in[3];
    const float* bet = (const float*)d_in[4];
    const float* wsp = (const float*)d_in[5];
    const float* bsp = (const float*)d_in[6];
    const float* w2  = (const float*)d_in[7];
    const float* b2  = (const float*)d_in[8];
    float* out = (float*)d_out;

    // ws layout: zb bf16[NPIX*64] (16.78 MB) | wtr bf16[4608*8] | stats f32[128]
    unsigned short* zb  = (unsigned short*)d_ws;
    unsigned short* wtr = zb + (size_t)NPIX * C_;
    float* stats = (float*)(wtr + 4608 * 8);

    // rb: bf16 pixel-major r, stored in d_out scratch (16.78 MB of 33.5 MB);
    // fully consumed by k1b/k3 before k4 overwrites d_out.
    unsigned short* rb = (unsigned short*)d_out;

    hipMemsetAsync(stats, 0, 128 * sizeof(float), stream);
    k0_wtr<<<18, 256, 0, stream>>>(w2, wtr);
    k1_r<<<NPIX / 256, 256, 0, stream>>>(x, wr, br, rb);
    k1b_stats<<<128, 256, 0, stream>>>(rb, stats);
    k3_involution<<<NPIX / 256, 256, 0, stream>>>(x, rb, stats, gam, bet, wsp, bsp, zb);
    k4_mfma<<<NPIX / 256, 256, 0, stream>>>(zb, wtr, b2, out);
}

// Round 5
// 162.319 us; speedup vs baseline: 3.0351x; 3.0351x over previous
//
#include <hip/hip_runtime.h>
#include <math.h>

#define H_ 128
#define W_ 128
#define C_ 64
#define B_ 8
#define HW 16384          // H_*W_
#define NPIX (B_*HW)      // 131072

typedef __attribute__((ext_vector_type(8))) short short8;
typedef __attribute__((ext_vector_type(4))) float f32x4;

__device__ __forceinline__ float softplus_fast(float v) {
    return fmaxf(v, 0.f) + __logf(1.f + __expf(-fabsf(v)));
}

__device__ __forceinline__ unsigned short f2bf(float f) {
    unsigned u = __builtin_bit_cast(unsigned, f);
    unsigned r = (u + 0x7fffu + ((u >> 16) & 1u)) >> 16;
    return (unsigned short)r;
}

// K0: transpose w2 [o][c][3][3] f32 -> bf16 MFMA A-fragments.
__global__ __launch_bounds__(256) void k0_wtr(const float* __restrict__ w2,
                                              unsigned short* __restrict__ wtr)
{
    int t = blockIdx.x * 256 + threadIdx.x;
    if (t >= 4 * 18 * 64) return;
    int lane = t & 63;
    int f    = (t >> 6) % 18;
    int wv   = t / (18 * 64);
    int koff = f >> 1, ch = f & 1;
    int o = wv * 16 + (lane & 15);
    int cb = ch * 32 + ((lane >> 4) << 3);
    uint4 pk;
    unsigned short* pv = (unsigned short*)&pk;
#pragma unroll
    for (int e = 0; e < 8; ++e)
        pv[e] = f2bf(w2[(size_t)o * 576 + (size_t)(cb + e) * 9 + koff]);
    *(uint4*)&wtr[(size_t)t * 8] = pk;
}

// K1: r = W_reduce @ x + b_reduce per pixel -> bf16 PIXEL-MAJOR [b][pix][c].
__global__ __launch_bounds__(256) void k1_r(
    const float* __restrict__ x, const float* __restrict__ wr,
    const float* __restrict__ br, unsigned short* __restrict__ rb)
{
    __shared__ float wrs[C_ * C_];
    __shared__ float brs[C_];
    int tid = threadIdx.x;
    for (int i = tid; i < C_ * C_; i += 256) wrs[i] = wr[i];
    if (tid < C_) brs[tid] = br[tid];
    __syncthreads();

    int pid = blockIdx.x * 256 + tid;
    int b   = pid >> 14;
    int rem = pid & (HW - 1);
    const float* xp = x + (((size_t)b * C_) << 14) + rem;

    float xv[C_];
#pragma unroll
    for (int c = 0; c < C_; ++c) xv[c] = xp[(size_t)c << 14];

    unsigned pkk[C_ / 2];
#pragma unroll
    for (int o = 0; o < C_; ++o) {
        float acc = brs[o];
        const float4* wro = reinterpret_cast<const float4*>(&wrs[o * C_]);
#pragma unroll
        for (int c4 = 0; c4 < C_ / 4; ++c4) {
            float4 wv = wro[c4];
            acc += wv.x * xv[4*c4] + wv.y * xv[4*c4+1]
                 + wv.z * xv[4*c4+2] + wv.w * xv[4*c4+3];
        }
        unsigned short bv = f2bf(acc);
        if (o & 1) pkk[o >> 1] |= ((unsigned)bv << 16);
        else       pkk[o >> 1]  = bv;
    }
    uint4* rp = (uint4*)(rb + ((size_t)pid << 6));
#pragma unroll
    for (int jj = 0; jj < 8; ++jj) rp[jj] = ((uint4*)pkk)[jj];
}

// K1b: per-channel sum/sumsq over rb (bf16 pixel-major).
__global__ __launch_bounds__(256) void k1b_stats(
    const unsigned short* __restrict__ rb, float* __restrict__ stats)
{
    __shared__ float ls[128];
    int tid = threadIdx.x;
    if (tid < 128) ls[tid] = 0.f;
    __syncthreads();

    int j   = tid & 7;
    int row = (blockIdx.x << 5) + (tid >> 3);
    float s[8] = {0,0,0,0,0,0,0,0}, q[8] = {0,0,0,0,0,0,0,0};
    for (int p = row; p < NPIX; p += (gridDim.x << 5)) {
        uint4 v = *(const uint4*)(rb + ((size_t)p << 6) + (j << 3));
        const unsigned* u = (const unsigned*)&v;
#pragma unroll
        for (int e = 0; e < 4; ++e) {
            float lo = __builtin_bit_cast(float, u[e] << 16);
            float hi = __builtin_bit_cast(float, u[e] & 0xffff0000u);
            s[2*e]   += lo; q[2*e]   += lo * lo;
            s[2*e+1] += hi; q[2*e+1] += hi * hi;
        }
    }
#pragma unroll
    for (int e = 0; e < 8; ++e) {
#pragma unroll
        for (int m = 8; m <= 32; m <<= 1) {
            s[e] += __shfl_xor(s[e], m, 64);
            q[e] += __shfl_xor(q[e], m, 64);
        }
    }
    int lane = tid & 63;
    if (lane < 8) {
#pragma unroll
        for (int e = 0; e < 8; ++e) {
            atomicAdd(&ls[lane * 8 + e], s[e]);
            atomicAdd(&ls[64 + lane * 8 + e], q[e]);
        }
    }
    __syncthreads();
    if (tid < 128) atomicAdd(&stats[tid], ls[tid]);
}

// K3: BN-fold inline; kern[9] streamed from r; involution; fast softplus.
// z accumulated in a per-thread 128B LDS row (16B-chunk XOR swizzle), then
// flushed as 8 contiguous uint4 stores -> full-line coalesced writes.
__global__ __launch_bounds__(256) void k3_involution(
    const float* __restrict__ x, const unsigned short* __restrict__ rb,
    const float* __restrict__ stats, const float* __restrict__ gamma,
    const float* __restrict__ beta, const float* __restrict__ wspan,
    const float* __restrict__ bspan, unsigned short* __restrict__ zb)
{
    __shared__ float wst[C_ * 12];
    __shared__ float a_s[C_], c_s[C_];
    __shared__ float xt[8][18][19];
    __shared__ unsigned zs[256 * 32];   // 32 KB z-staging, chunk-swizzled
    int tid = threadIdx.x;
    for (int i = tid; i < 9 * C_; i += 256) {
        int k = i >> 6, o = i & 63;
        wst[o * 12 + k] = wspan[i];
    }
    if (tid < C_) {
        float inv_n = 1.f / (float)NPIX;
        float mu  = stats[tid] * inv_n;
        float var = stats[C_ + tid] * inv_n - mu * mu;
        float is  = rsqrtf(var + 1e-5f);
        float a   = gamma[tid] * is;
        a_s[tid] = a;
        c_s[tid] = beta[tid] - mu * a;
    }

    int blk = blockIdx.x;
    int b = blk >> 6;
    int t = blk & 63;
    int h0 = (t >> 3) << 4;
    int w0 = (t & 7) << 4;
    int ty = tid >> 4, tx = tid & 15;
    int h = h0 + ty, w = w0 + tx;
    int pix = (h << 7) + w;
    int pid = (b << 14) + pix;
    size_t base_b = ((size_t)b * C_) << 14;

    __syncthreads();   // wst/a_s/c_s ready

    // kern[9]: stream r one uint4 at a time (nothing held in bulk)
    float kern[9];
#pragma unroll
    for (int k = 0; k < 9; ++k) kern[k] = bspan[k];

    const uint4* rp = (const uint4*)(rb + ((size_t)pid << 6));
#pragma unroll
    for (int jj = 0; jj < 8; ++jj) {
        uint4 v = rp[jj];
        const unsigned* u = (const unsigned*)&v;
#pragma unroll
        for (int e = 0; e < 4; ++e) {
            int o = jj * 8 + e * 2;
            float lo = __builtin_bit_cast(float, u[e] << 16);
            float hi = __builtin_bit_cast(float, u[e] & 0xffff0000u);
            float rn0 = fmaxf(a_s[o] * lo + c_s[o], 0.f);
            float rn1 = fmaxf(a_s[o + 1] * hi + c_s[o + 1], 0.f);
            const float* wo0 = &wst[o * 12];
            const float* wo1 = &wst[(o + 1) * 12];
#pragma unroll
            for (int k = 0; k < 9; ++k)
                kern[k] += wo0[k] * rn0 + wo1[k] * rn1;
        }
    }

#pragma unroll 1
    for (int c0 = 0; c0 < C_; c0 += 8) {
        __syncthreads();
        for (int idx = tid; idx < 8 * 324; idx += 256) {
            int c  = idx / 324;
            int r2 = idx - c * 324;
            int ly = r2 / 18, lx = r2 - ly * 18;
            int gh = h0 + ly - 1, gw = w0 + lx - 1;
            float v = 0.f;
            if ((unsigned)gh < 128u && (unsigned)gw < 128u)
                v = x[base_b + ((size_t)(c0 + c) << 14) + (gh << 7) + gw];
            xt[c][ly][lx] = v;
        }
        __syncthreads();
        unsigned pk[4];
#pragma unroll
        for (int cp = 0; cp < 4; ++cp) {
            float acc0 = 0.f, acc1 = 0.f;
#pragma unroll
            for (int i = 0; i < 3; ++i)
#pragma unroll
                for (int j = 0; j < 3; ++j) {
                    float kv = kern[i * 3 + j];
                    acc0 += kv * xt[2 * cp][ty + i][tx + j];
                    acc1 += kv * xt[2 * cp + 1][ty + i][tx + j];
                }
            pk[cp] = (unsigned)f2bf(softplus_fast(acc0))
                   | ((unsigned)f2bf(softplus_fast(acc1)) << 16);
        }
        // own-row LDS store, chunk-XOR swizzled (bank-conflict-free)
        *(uint4*)&zs[(tid << 5) + (((c0 >> 3) ^ (tid & 7)) << 2)] = *(uint4*)pk;
    }

    // flush own 128B row: contiguous full-line global write (no barrier
    // needed — same thread wrote these LDS words)
    uint4* zp = (uint4*)(zb + ((size_t)pid << 6));
#pragma unroll
    for (int k = 0; k < 8; ++k)
        zp[k] = *(const uint4*)&zs[(tid << 5) + ((k ^ (tid & 7)) << 2)];
}

// K4: dense 3x3 conv 64->64 via implicit-GEMM MFMA (bf16 in, f32 acc)
// + bias + softplus. 4 waves; wave w owns out-channels [16w,16w+16).
__global__ __launch_bounds__(256) void k4_mfma(
    const unsigned short* __restrict__ zb, const unsigned short* __restrict__ wtr,
    const float* __restrict__ b2, float* __restrict__ out)
{
    __shared__ unsigned short zt[324 * 64];   // 41,472 B, chunk-swizzled
    int tid = threadIdx.x;
    int blk = blockIdx.x;
    int b = blk >> 6;
    int t = blk & 63;
    int h0 = (t >> 3) << 4;
    int w0 = (t & 7) << 4;

    for (int idx = tid; idx < 324 * 8; idx += 256) {
        int p  = idx >> 3;
        int cg = idx & 7;
        int py = p / 18, px = p - py * 18;
        int gh = h0 + py - 1, gw = w0 + px - 1;
        uint4 v = make_uint4(0u, 0u, 0u, 0u);
        if ((unsigned)gh < 128u && (unsigned)gw < 128u)
            v = *(const uint4*)(zb + (((size_t)((b << 14) + (gh << 7) + gw)) << 6) + (cg << 3));
        *(uint4*)&zt[(p << 6) + ((cg ^ (p & 7)) << 3)] = v;
    }

    int wid  = tid >> 6, lane = tid & 63;
    int nl   = lane & 15;
    int kg   = lane >> 4;

    short8 wf[18];
    const short8* wp = (const short8*)wtr;
#pragma unroll
    for (int f = 0; f < 18; ++f)
        wf[f] = wp[(size_t)(wid * 18 + f) * 64 + lane];

    f32x4 acc[16];
#pragma unroll
    for (int nt = 0; nt < 16; ++nt) acc[nt] = (f32x4){0.f, 0.f, 0.f, 0.f};

    __syncthreads();

#pragma unroll
    for (int y = 0; y < 18; ++y) {
        short8 bf[6];
#pragma unroll
        for (int j = 0; j < 3; ++j)
#pragma unroll
            for (int ch = 0; ch < 2; ++ch) {
                int p  = y * 18 + j + nl;
                int cg = ch * 4 + kg;
                bf[j * 2 + ch] = *(const short8*)&zt[(p << 6) + ((cg ^ (p & 7)) << 3)];
            }
#pragma unroll
        for (int i = 0; i < 3; ++i) {
            int nt = y - i;
            if (nt >= 0 && nt < 16) {
#pragma unroll
                for (int j = 0; j < 3; ++j)
#pragma unroll
                    for (int ch = 0; ch < 2; ++ch)
                        acc[nt] = __builtin_amdgcn_mfma_f32_16x16x32_bf16(
                            wf[(i * 3 + j) * 2 + ch], bf[j * 2 + ch], acc[nt], 0, 0, 0);
            }
        }
    }

    float bias[4];
#pragma unroll
    for (int r = 0; r < 4; ++r) bias[r] = b2[(wid << 4) + (kg << 2) + r];

    size_t ob = ((size_t)b) << 20;
#pragma unroll
    for (int nt = 0; nt < 16; ++nt) {
        int h = h0 + nt;
#pragma unroll
        for (int r = 0; r < 4; ++r) {
            int o = (wid << 4) + (kg << 2) + r;
            float v = acc[nt][r] + bias[r];
            out[ob + ((size_t)o << 14) + (h << 7) + w0 + nl] = softplus_fast(v);
        }
    }
}

extern "C" void kernel_launch(void* const* d_in, const int* in_sizes, int n_in,
                              void* d_out, int out_size, void* d_ws, size_t ws_size,
                              hipStream_t stream)
{
    const float* x   = (const float*)d_in[0];
    const float* wr  = (const float*)d_in[1];
    const float* br  = (const float*)d_in[2];
    const float* gam = (const float*)d_in[3];
    const float* bet = (const float*)d_in[4];
    const float* wsp = (const float*)d_in[5];
    const float* bsp = (const float*)d_in[6];
    const float* w2  = (const float*)d_in[7];
    const float* b2  = (const float*)d_in[8];
    float* out = (float*)d_out;

    // ws layout: zb bf16[NPIX*64] (16.78 MB) | wtr bf16[4608*8] | stats f32[128]
    unsigned short* zb  = (unsigned short*)d_ws;
    unsigned short* wtr = zb + (size_t)NPIX * C_;
    float* stats = (float*)(wtr + 4608 * 8);

    // rb: bf16 pixel-major r in d_out scratch; fully consumed before k4.
    unsigned short* rb = (unsigned short*)d_out;

    hipMemsetAsync(stats, 0, 128 * sizeof(float), stream);
    k0_wtr<<<18, 256, 0, stream>>>(w2, wtr);
    k1_r<<<NPIX / 256, 256, 0, stream>>>(x, wr, br, rb);
    k1b_stats<<<128, 256, 0, stream>>>(rb, stats);
    k3_involution<<<NPIX / 256, 256, 0, stream>>>(x, rb, stats, gam, bet, wsp, bsp, zb);
    k4_mfma<<<NPIX / 256, 256, 0, stream>>>(zb, wtr, b2, out);
}

// Round 6
// 114.457 us; speedup vs baseline: 4.3043x; 1.4182x over previous
//
#include <hip/hip_runtime.h>
#include <math.h>

#define H_ 128
#define W_ 128
#define C_ 64
#define B_ 8
#define HW 16384          // H_*W_
#define NPIX (B_*HW)      // 131072

typedef __attribute__((ext_vector_type(8))) short short8;
typedef __attribute__((ext_vector_type(4))) float f32x4;

__device__ __forceinline__ float softplus_fast(float v) {
    return fmaxf(v, 0.f) + __logf(1.f + __expf(-fabsf(v)));
}

__device__ __forceinline__ unsigned short f2bf(float f) {
    unsigned u = __builtin_bit_cast(unsigned, f);
    unsigned r = (u + 0x7fffu + ((u >> 16) & 1u)) >> 16;
    return (unsigned short)r;
}

// K0: (a) transpose w2 [o][c][3][3] f32 -> bf16 MFMA A-fragments (wtr);
//     (b) blocks 0-1 also transpose w_reduce [o][c] -> bf16 A-frags (wtr1).
__global__ __launch_bounds__(256) void k0_wtr(const float* __restrict__ w2,
                                              const float* __restrict__ wr,
                                              unsigned short* __restrict__ wtr,
                                              unsigned short* __restrict__ wtr1)
{
    int t = blockIdx.x * 256 + threadIdx.x;
    if (t < 512) {
        // wtr1: frag f = mt*2+kh; o = mt*16+(lane&15), c = kh*32+(lane>>4)*8+e
        int lane = t & 63, f = t >> 6;
        int mt = f >> 1, kh = f & 1;
        int o  = mt * 16 + (lane & 15);
        int c0 = kh * 32 + ((lane >> 4) << 3);
        uint4 pk;
        unsigned short* pv = (unsigned short*)&pk;
#pragma unroll
        for (int e = 0; e < 8; ++e)
            pv[e] = f2bf(wr[o * C_ + c0 + e]);
        *(uint4*)&wtr1[(size_t)t * 8] = pk;
    }
    if (t >= 4 * 18 * 64) return;
    int lane = t & 63;
    int f    = (t >> 6) % 18;
    int wv   = t / (18 * 64);
    int koff = f >> 1, ch = f & 1;
    int o = wv * 16 + (lane & 15);
    int cb = ch * 32 + ((lane >> 4) << 3);
    uint4 pk;
    unsigned short* pv = (unsigned short*)&pk;
#pragma unroll
    for (int e = 0; e < 8; ++e)
        pv[e] = f2bf(w2[(size_t)o * 576 + (size_t)(cb + e) * 9 + koff]);
    *(uint4*)&wtr[(size_t)t * 8] = pk;
}

// K1: r = W_reduce @ x + b_reduce via MFMA implicit GEMM.
// 256 px/block; x staged to swizzled pixel-major bf16 LDS; 4 waves x 64 px;
// rb written bf16 pixel-major as contiguous 128B/thread.
__global__ __launch_bounds__(256) void k1_mfma(
    const float* __restrict__ x, const unsigned short* __restrict__ wtr1,
    const float* __restrict__ br, unsigned short* __restrict__ rb)
{
    __shared__ unsigned short xb[256 * 64];   // 32KB, chunk-XOR swizzled
    __shared__ float brs[C_];
    int tid = threadIdx.x;
    int blk = blockIdx.x;
    int pid0 = blk << 8;
    int b    = pid0 >> 14;
    int rem0 = pid0 & (HW - 1);
    const float* xbase = x + (((size_t)b * C_) << 14) + rem0;

    if (tid < C_) brs[tid] = br[tid];

    // stage: thread owns pixel p=tid; 64 coalesced dword loads (lane=pixel),
    // pack 8 ch -> ds_write_b128 at chunk m ^ (p&7)  (conflict-free: p&7 spans 8)
    int p = tid;
#pragma unroll
    for (int m = 0; m < 8; ++m) {
        float tmp[8];
#pragma unroll
        for (int e = 0; e < 8; ++e)
            tmp[e] = xbase[((size_t)(m * 8 + e) << 14) + p];
        unsigned pk[4];
#pragma unroll
        for (int e = 0; e < 4; ++e)
            pk[e] = (unsigned)f2bf(tmp[2 * e]) | ((unsigned)f2bf(tmp[2 * e + 1]) << 16);
        *(uint4*)&xb[(p << 6) + ((m ^ (p & 7)) << 3)] = *(uint4*)pk;
    }

    int wid = tid >> 6, lane = tid & 63;
    int nl  = lane & 15;
    int kg  = lane >> 4;

    short8 af[8];
    const short8* wp = (const short8*)wtr1;
#pragma unroll
    for (int f = 0; f < 8; ++f) af[f] = wp[f * 64 + lane];

    f32x4 acc[4][4];
#pragma unroll
    for (int mt = 0; mt < 4; ++mt)
#pragma unroll
        for (int nt = 0; nt < 4; ++nt) acc[mt][nt] = (f32x4){0.f, 0.f, 0.f, 0.f};

    __syncthreads();

    int nbase = wid << 6;
#pragma unroll
    for (int nt = 0; nt < 4; ++nt) {
        int pp = nbase + (nt << 4) + nl;
#pragma unroll
        for (int kh = 0; kh < 2; ++kh) {
            int m = kh * 4 + kg;
            short8 bf = *(const short8*)&xb[(pp << 6) + ((m ^ (pp & 7)) << 3)];
#pragma unroll
            for (int mt = 0; mt < 4; ++mt)
                acc[mt][nt] = __builtin_amdgcn_mfma_f32_16x16x32_bf16(
                    af[mt * 2 + kh], bf, acc[mt][nt], 0, 0, 0);
        }
    }

    __syncthreads();   // all MFMA reads of xb done before overwrite

    // epilogue: bias, pack, write back into xb (same swizzle), C/D layout:
    // col = nl (pixel), row = kg*4 + r (channel within 16-tile)
#pragma unroll
    for (int mt = 0; mt < 4; ++mt) {
        int c = (mt << 4) + (kg << 2);       // first of 4 consecutive channels
        float b0 = brs[c], b1 = brs[c + 1], b2v = brs[c + 2], b3 = brs[c + 3];
        int chunk = c >> 3;                   // = 2*mt + (kg>>1)
#pragma unroll
        for (int nt = 0; nt < 4; ++nt) {
            int pp = nbase + (nt << 4) + nl;
            f32x4 a = acc[mt][nt];
            unsigned lo = (unsigned)f2bf(a[0] + b0) | ((unsigned)f2bf(a[1] + b1) << 16);
            unsigned hi = (unsigned)f2bf(a[2] + b2v) | ((unsigned)f2bf(a[3] + b3) << 16);
            unsigned* dst = (unsigned*)&xb[(pp << 6) + ((chunk ^ (pp & 7)) << 3) + ((kg & 1) << 2)];
            dst[0] = lo;
            dst[1] = hi;
        }
    }
    __syncthreads();

    // flush own pixel row: 8 swizzled b128 reads -> contiguous 128B store
    uint4* rp = (uint4*)(rb + ((size_t)(pid0 + p) << 6));
#pragma unroll
    for (int m = 0; m < 8; ++m)
        rp[m] = *(const uint4*)&xb[(p << 6) + ((m ^ (p & 7)) << 3)];
}

// K1b: per-channel sum/sumsq over rb (bf16 pixel-major).
__global__ __launch_bounds__(256) void k1b_stats(
    const unsigned short* __restrict__ rb, float* __restrict__ stats)
{
    __shared__ float ls[128];
    int tid = threadIdx.x;
    if (tid < 128) ls[tid] = 0.f;
    __syncthreads();

    int j   = tid & 7;
    int row = (blockIdx.x << 5) + (tid >> 3);
    float s[8] = {0,0,0,0,0,0,0,0}, q[8] = {0,0,0,0,0,0,0,0};
    for (int p = row; p < NPIX; p += (gridDim.x << 5)) {
        uint4 v = *(const uint4*)(rb + ((size_t)p << 6) + (j << 3));
        const unsigned* u = (const unsigned*)&v;
#pragma unroll
        for (int e = 0; e < 4; ++e) {
            float lo = __builtin_bit_cast(float, u[e] << 16);
            float hi = __builtin_bit_cast(float, u[e] & 0xffff0000u);
            s[2*e]   += lo; q[2*e]   += lo * lo;
            s[2*e+1] += hi; q[2*e+1] += hi * hi;
        }
    }
#pragma unroll
    for (int e = 0; e < 8; ++e) {
#pragma unroll
        for (int m = 8; m <= 32; m <<= 1) {
            s[e] += __shfl_xor(s[e], m, 64);
            q[e] += __shfl_xor(q[e], m, 64);
        }
    }
    int lane = tid & 63;
    if (lane < 8) {
#pragma unroll
        for (int e = 0; e < 8; ++e) {
            atomicAdd(&ls[lane * 8 + e], s[e]);
            atomicAdd(&ls[64 + lane * 8 + e], q[e]);
        }
    }
    __syncthreads();
    if (tid < 128) atomicAdd(&stats[tid], ls[tid]);
}

// K3: BN-fold inline; kern[9] streamed from r; involution; fast softplus.
// z accumulated in a per-thread 128B LDS row (16B-chunk XOR swizzle), then
// flushed as 8 contiguous uint4 stores -> full-line coalesced writes.
__global__ __launch_bounds__(256) void k3_involution(
    const float* __restrict__ x, const unsigned short* __restrict__ rb,
    const float* __restrict__ stats, const float* __restrict__ gamma,
    const float* __restrict__ beta, const float* __restrict__ wspan,
    const float* __restrict__ bspan, unsigned short* __restrict__ zb)
{
    __shared__ float wst[C_ * 12];
    __shared__ float a_s[C_], c_s[C_];
    __shared__ float xt[8][18][19];
    __shared__ unsigned zs[256 * 32];   // 32 KB z-staging, chunk-swizzled
    int tid = threadIdx.x;
    for (int i = tid; i < 9 * C_; i += 256) {
        int k = i >> 6, o = i & 63;
        wst[o * 12 + k] = wspan[i];
    }
    if (tid < C_) {
        float inv_n = 1.f / (float)NPIX;
        float mu  = stats[tid] * inv_n;
        float var = stats[C_ + tid] * inv_n - mu * mu;
        float is  = rsqrtf(var + 1e-5f);
        float a   = gamma[tid] * is;
        a_s[tid] = a;
        c_s[tid] = beta[tid] - mu * a;
    }

    int blk = blockIdx.x;
    int b = blk >> 6;
    int t = blk & 63;
    int h0 = (t >> 3) << 4;
    int w0 = (t & 7) << 4;
    int ty = tid >> 4, tx = tid & 15;
    int h = h0 + ty, w = w0 + tx;
    int pix = (h << 7) + w;
    int pid = (b << 14) + pix;
    size_t base_b = ((size_t)b * C_) << 14;

    __syncthreads();   // wst/a_s/c_s ready

    float kern[9];
#pragma unroll
    for (int k = 0; k < 9; ++k) kern[k] = bspan[k];

    const uint4* rp = (const uint4*)(rb + ((size_t)pid << 6));
#pragma unroll
    for (int jj = 0; jj < 8; ++jj) {
        uint4 v = rp[jj];
        const unsigned* u = (const unsigned*)&v;
#pragma unroll
        for (int e = 0; e < 4; ++e) {
            int o = jj * 8 + e * 2;
            float lo = __builtin_bit_cast(float, u[e] << 16);
            float hi = __builtin_bit_cast(float, u[e] & 0xffff0000u);
            float rn0 = fmaxf(a_s[o] * lo + c_s[o], 0.f);
            float rn1 = fmaxf(a_s[o + 1] * hi + c_s[o + 1], 0.f);
            const float* wo0 = &wst[o * 12];
            const float* wo1 = &wst[(o + 1) * 12];
#pragma unroll
            for (int k = 0; k < 9; ++k)
                kern[k] += wo0[k] * rn0 + wo1[k] * rn1;
        }
    }

#pragma unroll 1
    for (int c0 = 0; c0 < C_; c0 += 8) {
        __syncthreads();
        for (int idx = tid; idx < 8 * 324; idx += 256) {
            int c  = idx / 324;
            int r2 = idx - c * 324;
            int ly = r2 / 18, lx = r2 - ly * 18;
            int gh = h0 + ly - 1, gw = w0 + lx - 1;
            float v = 0.f;
            if ((unsigned)gh < 128u && (unsigned)gw < 128u)
                v = x[base_b + ((size_t)(c0 + c) << 14) + (gh << 7) + gw];
            xt[c][ly][lx] = v;
        }
        __syncthreads();
        unsigned pk[4];
#pragma unroll
        for (int cp = 0; cp < 4; ++cp) {
            float acc0 = 0.f, acc1 = 0.f;
#pragma unroll
            for (int i = 0; i < 3; ++i)
#pragma unroll
                for (int j = 0; j < 3; ++j) {
                    float kv = kern[i * 3 + j];
                    acc0 += kv * xt[2 * cp][ty + i][tx + j];
                    acc1 += kv * xt[2 * cp + 1][ty + i][tx + j];
                }
            pk[cp] = (unsigned)f2bf(softplus_fast(acc0))
                   | ((unsigned)f2bf(softplus_fast(acc1)) << 16);
        }
        *(uint4*)&zs[(tid << 5) + (((c0 >> 3) ^ (tid & 7)) << 2)] = *(uint4*)pk;
    }

    uint4* zp = (uint4*)(zb + ((size_t)pid << 6));
#pragma unroll
    for (int k = 0; k < 8; ++k)
        zp[k] = *(const uint4*)&zs[(tid << 5) + ((k ^ (tid & 7)) << 2)];
}

// K4: dense 3x3 conv 64->64 via implicit-GEMM MFMA (bf16 in, f32 acc)
// + bias + softplus. 4 waves; wave w owns out-channels [16w,16w+16).
__global__ __launch_bounds__(256) void k4_mfma(
    const unsigned short* __restrict__ zb, const unsigned short* __restrict__ wtr,
    const float* __restrict__ b2, float* __restrict__ out)
{
    __shared__ unsigned short zt[324 * 64];   // 41,472 B, chunk-swizzled
    int tid = threadIdx.x;
    int blk = blockIdx.x;
    int b = blk >> 6;
    int t = blk & 63;
    int h0 = (t >> 3) << 4;
    int w0 = (t & 7) << 4;

    for (int idx = tid; idx < 324 * 8; idx += 256) {
        int p  = idx >> 3;
        int cg = idx & 7;
        int py = p / 18, px = p - py * 18;
        int gh = h0 + py - 1, gw = w0 + px - 1;
        uint4 v = make_uint4(0u, 0u, 0u, 0u);
        if ((unsigned)gh < 128u && (unsigned)gw < 128u)
            v = *(const uint4*)(zb + (((size_t)((b << 14) + (gh << 7) + gw)) << 6) + (cg << 3));
        *(uint4*)&zt[(p << 6) + ((cg ^ (p & 7)) << 3)] = v;
    }

    int wid  = tid >> 6, lane = tid & 63;
    int nl   = lane & 15;
    int kg   = lane >> 4;

    short8 wf[18];
    const short8* wp = (const short8*)wtr;
#pragma unroll
    for (int f = 0; f < 18; ++f)
        wf[f] = wp[(size_t)(wid * 18 + f) * 64 + lane];

    f32x4 acc[16];
#pragma unroll
    for (int nt = 0; nt < 16; ++nt) acc[nt] = (f32x4){0.f, 0.f, 0.f, 0.f};

    __syncthreads();

#pragma unroll
    for (int y = 0; y < 18; ++y) {
        short8 bf[6];
#pragma unroll
        for (int j = 0; j < 3; ++j)
#pragma unroll
            for (int ch = 0; ch < 2; ++ch) {
                int p  = y * 18 + j + nl;
                int cg = ch * 4 + kg;
                bf[j * 2 + ch] = *(const short8*)&zt[(p << 6) + ((cg ^ (p & 7)) << 3)];
            }
#pragma unroll
        for (int i = 0; i < 3; ++i) {
            int nt = y - i;
            if (nt >= 0 && nt < 16) {
#pragma unroll
                for (int j = 0; j < 3; ++j)
#pragma unroll
                    for (int ch = 0; ch < 2; ++ch)
                        acc[nt] = __builtin_amdgcn_mfma_f32_16x16x32_bf16(
                            wf[(i * 3 + j) * 2 + ch], bf[j * 2 + ch], acc[nt], 0, 0, 0);
            }
        }
    }

    float bias[4];
#pragma unroll
    for (int r = 0; r < 4; ++r) bias[r] = b2[(wid << 4) + (kg << 2) + r];

    size_t ob = ((size_t)b) << 20;
#pragma unroll
    for (int nt = 0; nt < 16; ++nt) {
        int h = h0 + nt;
#pragma unroll
        for (int r = 0; r < 4; ++r) {
            int o = (wid << 4) + (kg << 2) + r;
            float v = acc[nt][r] + bias[r];
            out[ob + ((size_t)o << 14) + (h << 7) + w0 + nl] = softplus_fast(v);
        }
    }
}

extern "C" void kernel_launch(void* const* d_in, const int* in_sizes, int n_in,
                              void* d_out, int out_size, void* d_ws, size_t ws_size,
                              hipStream_t stream)
{
    const float* x   = (const float*)d_in[0];
    const float* wr  = (const float*)d_in[1];
    const float* br  = (const float*)d_in[2];
    const float* gam = (const float*)d_in[3];
    const float* bet = (const float*)d_in[4];
    const float* wsp = (const float*)d_in[5];
    const float* bsp = (const float*)d_in[6];
    const float* w2  = (const float*)d_in[7];
    const float* b2  = (const float*)d_in[8];
    float* out = (float*)d_out;

    // ws layout: zb bf16[NPIX*64] | wtr bf16[4608*8] | wtr1 bf16[512*8] | stats f32[128]
    unsigned short* zb   = (unsigned short*)d_ws;
    unsigned short* wtr  = zb + (size_t)NPIX * C_;
    unsigned short* wtr1 = wtr + 4608 * 8;
    float* stats = (float*)(wtr1 + 512 * 8);

    // rb: bf16 pixel-major r in d_out scratch; fully consumed before k4.
    unsigned short* rb = (unsigned short*)d_out;

    hipMemsetAsync(stats, 0, 128 * sizeof(float), stream);
    k0_wtr<<<18, 256, 0, stream>>>(w2, wr, wtr, wtr1);
    k1_mfma<<<NPIX / 256, 256, 0, stream>>>(x, wtr1, br, rb);
    k1b_stats<<<128, 256, 0, stream>>>(rb, stats);
    k3_involution<<<NPIX / 256, 256, 0, stream>>>(x, rb, stats, gam, bet, wsp, bsp, zb);
    k4_mfma<<<NPIX / 256, 256, 0, stream>>>(zb, wtr, b2, out);
}